// Round 1
// baseline (879.677 us; speedup 1.0000x reference)
//
#include <hip/hip_runtime.h>

#define N_IN 5
#define N_OUT 16

// ---------------------------------------------------------------------------
// Kernel 1: x = atom @ W^T + b  (per node), and deg[i] = 1 (self loop seed).
// W (16x5=80 floats) + b (16) are wave-uniform reads -> L1 broadcast.
// ---------------------------------------------------------------------------
__global__ void linear_deg_init(const float* __restrict__ atom,
                                const float* __restrict__ W,
                                const float* __restrict__ b,
                                float* __restrict__ x,
                                float* __restrict__ deg,
                                int n) {
    int i = blockIdx.x * blockDim.x + threadIdx.x;
    if (i >= n) return;
    float a[N_IN];
#pragma unroll
    for (int k = 0; k < N_IN; ++k) a[k] = atom[(long long)i * N_IN + k];
#pragma unroll
    for (int o = 0; o < N_OUT; ++o) {
        float acc = b[o];
#pragma unroll
        for (int k = 0; k < N_IN; ++k) acc = fmaf(a[k], W[o * N_IN + k], acc);
        x[(long long)i * N_OUT + o] = acc;
    }
    deg[i] = 1.0f;
}

// ---------------------------------------------------------------------------
// Kernel 2: deg[col[e]] += 1 for each edge (targets).
// ---------------------------------------------------------------------------
__global__ void deg_accum(const int* __restrict__ col,
                          float* __restrict__ deg,
                          int e) {
    int i = blockIdx.x * blockDim.x + threadIdx.x;
    if (i < e) atomicAdd(&deg[col[i]], 1.0f);
}

// ---------------------------------------------------------------------------
// Kernel 3: dis = 1/sqrt(deg) (stored in place of deg); initialize out with
// the self-loop term dis^2 * x[i]  (plain store -> clears 0xAA poison).
// ---------------------------------------------------------------------------
__global__ void dis_selfloop(const float* __restrict__ x,
                             float* __restrict__ deg_dis,
                             float* __restrict__ out,
                             int n) {
    int i = blockIdx.x * blockDim.x + threadIdx.x;
    if (i >= n) return;
    float d = deg_dis[i];
    float dis = 1.0f / sqrtf(d);
    deg_dis[i] = dis;
    float s = dis * dis;
    const float4* x4 = (const float4*)(x + (long long)i * N_OUT);
    float4* o4 = (float4*)(out + (long long)i * N_OUT);
#pragma unroll
    for (int q = 0; q < 4; ++q) {
        float4 v = x4[q];
        v.x *= s; v.y *= s; v.z *= s; v.w *= s;
        o4[q] = v;
    }
}

// ---------------------------------------------------------------------------
// Kernel 4: per edge: out[col] += dis[row]*dis[col] * x[row]
// 4 threads per edge, each handling a float4 slice of the 16 outputs.
// ---------------------------------------------------------------------------
__global__ void edge_scatter(const int* __restrict__ row,
                             const int* __restrict__ col,
                             const float* __restrict__ dis,
                             const float* __restrict__ x,
                             float* __restrict__ out,
                             int e) {
    long long t = (long long)blockIdx.x * blockDim.x + threadIdx.x;
    int eid = (int)(t >> 2);
    int q = (int)(t & 3);
    if (eid >= e) return;
    int r = row[eid];
    int c = col[eid];
    float norm = dis[r] * dis[c];
    float4 v = ((const float4*)(x + (long long)r * N_OUT))[q];
    float* op = out + (long long)c * N_OUT + q * 4;
    atomicAdd(op + 0, norm * v.x);
    atomicAdd(op + 1, norm * v.y);
    atomicAdd(op + 2, norm * v.z);
    atomicAdd(op + 3, norm * v.w);
}

// ---------------------------------------------------------------------------
// Kernel 5: out = relu(out), float4.
// ---------------------------------------------------------------------------
__global__ void relu_kernel(float* __restrict__ out, int total4) {
    int i = blockIdx.x * blockDim.x + threadIdx.x;
    if (i < total4) {
        float4 v = ((float4*)out)[i];
        v.x = fmaxf(v.x, 0.0f);
        v.y = fmaxf(v.y, 0.0f);
        v.z = fmaxf(v.z, 0.0f);
        v.w = fmaxf(v.w, 0.0f);
        ((float4*)out)[i] = v;
    }
}

extern "C" void kernel_launch(void* const* d_in, const int* in_sizes, int n_in,
                              void* d_out, int out_size, void* d_ws, size_t ws_size,
                              hipStream_t stream) {
    const float* atom = (const float*)d_in[0];
    const int*   eidx = (const int*)d_in[1];   // [2, E] int32: row then col
    const float* W    = (const float*)d_in[2];
    const float* b    = (const float*)d_in[3];
    float* out = (float*)d_out;

    int n = in_sizes[0] / N_IN;       // 100000
    int e = in_sizes[1] / 2;          // 3200000
    const int* row = eidx;
    const int* col = eidx + e;

    // Workspace layout: x [n*16] floats, then deg/dis [n] floats.
    float* x   = (float*)d_ws;
    float* deg = x + (size_t)n * N_OUT;

    const int B = 256;

    linear_deg_init<<<(n + B - 1) / B, B, 0, stream>>>(atom, W, b, x, deg, n);
    deg_accum<<<(e + B - 1) / B, B, 0, stream>>>(col, deg, e);
    dis_selfloop<<<(n + B - 1) / B, B, 0, stream>>>(x, deg, out, n);

    long long scatter_threads = 4LL * e;
    edge_scatter<<<(int)((scatter_threads + B - 1) / B), B, 0, stream>>>(
        row, col, deg, x, out, e);

    int total4 = n * N_OUT / 4;
    relu_kernel<<<(total4 + B - 1) / B, B, 0, stream>>>(out, total4);
}

// Round 2
// 541.863 us; speedup vs baseline: 1.6234x; 1.6234x over previous
//
#include <hip/hip_runtime.h>

#define N_IN 5
#define N_OUT 16

// ---------------------------------------------------------------------------
// Kernel 1: x = atom @ W^T + b (per node). Also zero-init cnt[] (ws poisoned).
// ---------------------------------------------------------------------------
__global__ void linear_x(const float* __restrict__ atom,
                         const float* __restrict__ W,
                         const float* __restrict__ b,
                         float* __restrict__ x,
                         int* __restrict__ cnt,
                         int n) {
    int i = blockIdx.x * blockDim.x + threadIdx.x;
    if (i >= n) return;
    float a[N_IN];
#pragma unroll
    for (int k = 0; k < N_IN; ++k) a[k] = atom[(long long)i * N_IN + k];
#pragma unroll
    for (int o = 0; o < N_OUT; ++o) {
        float acc = b[o];
#pragma unroll
        for (int k = 0; k < N_IN; ++k) acc = fmaf(a[k], W[o * N_IN + k], acc);
        x[(long long)i * N_OUT + o] = acc;
    }
    cnt[i] = 0;
}

// ---------------------------------------------------------------------------
// Kernel 2: in-degree count over targets (int atomics, 1 per edge).
// ---------------------------------------------------------------------------
__global__ void count_kernel(const int* __restrict__ col,
                             int* __restrict__ cnt, int e) {
    int i = blockIdx.x * blockDim.x + threadIdx.x;
    if (i < e) atomicAdd(&cnt[col[i]], 1);
}

// ---------------------------------------------------------------------------
// Kernels 3-5: hierarchical exclusive scan of cnt -> off (CSR offsets).
// ---------------------------------------------------------------------------
__global__ void scan_block(const int* __restrict__ cnt, int* __restrict__ off,
                           int* __restrict__ bsum, int n) {
    __shared__ int s[256];
    int tid = threadIdx.x;
    int i = blockIdx.x * 256 + tid;
    int v = (i < n) ? cnt[i] : 0;
    s[tid] = v;
    __syncthreads();
    for (int d = 1; d < 256; d <<= 1) {
        int t = (tid >= d) ? s[tid - d] : 0;
        __syncthreads();
        s[tid] += t;
        __syncthreads();
    }
    if (i < n) off[i] = s[tid] - v;           // exclusive within block
    if (tid == 255) bsum[blockIdx.x] = s[255]; // block total
}

__global__ void scan_sums(int* __restrict__ bsum, int nb) {
    __shared__ int s[512];
    int tid = threadIdx.x;
    int v = (tid < nb) ? bsum[tid] : 0;
    s[tid] = v;
    __syncthreads();
    for (int d = 1; d < 512; d <<= 1) {
        int t = (tid >= d) ? s[tid - d] : 0;
        __syncthreads();
        s[tid] += t;
        __syncthreads();
    }
    if (tid < nb) bsum[tid] = s[tid] - v;     // exclusive over block totals
}

// off[i] += block base; cursor[i] = off[i]; dis[i] = 1/sqrt(cnt+1) (self loop).
__global__ void scan_add(const int* __restrict__ cnt, int* __restrict__ off,
                         const int* __restrict__ bsum, int* __restrict__ cursor,
                         float* __restrict__ dis, int n) {
    int i = blockIdx.x * blockDim.x + threadIdx.x;
    if (i >= n) return;
    int o = off[i] + bsum[i >> 8];
    off[i] = o;
    cursor[i] = o;
    dis[i] = rsqrtf((float)(cnt[i] + 1));
}

// ---------------------------------------------------------------------------
// Kernel 6: CSR bucket fill — one int atomic per edge for slot allocation.
// ---------------------------------------------------------------------------
__global__ void fill_kernel(const int* __restrict__ row, const int* __restrict__ col,
                            int* __restrict__ cursor, int* __restrict__ bucket, int e) {
    int i = blockIdx.x * blockDim.x + threadIdx.x;
    if (i >= e) return;
    int c = col[i];
    int p = atomicAdd(&cursor[c], 1);
    bucket[p] = row[i];
}

// ---------------------------------------------------------------------------
// Kernel 7: gather + self-loop + ReLU. 4 lanes per node, float4 slice each.
// Single plain store per lane — zero float atomics.
// ---------------------------------------------------------------------------
__global__ void gather_kernel(const int* __restrict__ off, const int* __restrict__ cnt,
                              const int* __restrict__ bucket, const float* __restrict__ dis,
                              const float* __restrict__ x, float* __restrict__ out, int n) {
    int t = blockIdx.x * blockDim.x + threadIdx.x;
    int node = t >> 2;
    int q = t & 3;
    if (node >= n) return;
    float dc = dis[node];
    int o = off[node];
    int m = cnt[node];
    const float4* xq = (const float4*)x;
    float4 vs = xq[node * 4 + q];
    float s = dc * dc;                         // self-loop norm (deg>=1)
    float4 acc = make_float4(s * vs.x, s * vs.y, s * vs.z, s * vs.w);
    for (int k = 0; k < m; ++k) {
        int r = bucket[o + k];
        float nm = dc * dis[r];
        float4 v = xq[r * 4 + q];
        acc.x = fmaf(nm, v.x, acc.x);
        acc.y = fmaf(nm, v.y, acc.y);
        acc.z = fmaf(nm, v.z, acc.z);
        acc.w = fmaf(nm, v.w, acc.w);
    }
    acc.x = fmaxf(acc.x, 0.0f);
    acc.y = fmaxf(acc.y, 0.0f);
    acc.z = fmaxf(acc.z, 0.0f);
    acc.w = fmaxf(acc.w, 0.0f);
    ((float4*)out)[node * 4 + q] = acc;
}

extern "C" void kernel_launch(void* const* d_in, const int* in_sizes, int n_in,
                              void* d_out, int out_size, void* d_ws, size_t ws_size,
                              hipStream_t stream) {
    const float* atom = (const float*)d_in[0];
    const int*   eidx = (const int*)d_in[1];   // [2, E] int32: row then col
    const float* W    = (const float*)d_in[2];
    const float* b    = (const float*)d_in[3];
    float* out = (float*)d_out;

    int n = in_sizes[0] / N_IN;       // 100000
    int e = in_sizes[1] / 2;          // 3200000
    const int* row = eidx;
    const int* col = eidx + e;

    // Workspace layout (all 256B-aligned):
    //   x[n*16] f32 | dis[n] f32 | cnt[n] i32 | off[n] i32 | cursor[n] i32
    //   bsum[512] i32 | bucket[e] i32        total ~21 MB
    char* w = (char*)d_ws;
    auto align256 = [](size_t v) { return (v + 255) & ~(size_t)255; };
    float* x      = (float*)w;                         w += align256((size_t)n * N_OUT * 4);
    float* dis    = (float*)w;                         w += align256((size_t)n * 4);
    int*   cnt    = (int*)w;                           w += align256((size_t)n * 4);
    int*   off    = (int*)w;                           w += align256((size_t)n * 4);
    int*   cursor = (int*)w;                           w += align256((size_t)n * 4);
    int*   bsum   = (int*)w;                           w += align256(512 * 4);
    int*   bucket = (int*)w;

    const int B = 256;
    int nb = (n + 255) / 256;  // 391 <= 512, fits scan_sums

    linear_x<<<(n + B - 1) / B, B, 0, stream>>>(atom, W, b, x, cnt, n);
    count_kernel<<<(e + B - 1) / B, B, 0, stream>>>(col, cnt, e);
    scan_block<<<nb, 256, 0, stream>>>(cnt, off, bsum, n);
    scan_sums<<<1, 512, 0, stream>>>(bsum, nb);
    scan_add<<<(n + B - 1) / B, B, 0, stream>>>(cnt, off, bsum, cursor, dis, n);
    fill_kernel<<<(e + B - 1) / B, B, 0, stream>>>(row, col, cursor, bucket, e);
    gather_kernel<<<(4 * n + B - 1) / B, B, 0, stream>>>(off, cnt, bucket, dis, x, out, n);
}

// Round 3
// 249.675 us; speedup vs baseline: 3.5233x; 2.1703x over previous
//
#include <hip/hip_runtime.h>

#define N_IN 5
#define N_OUT 16
#define BIN_NODES 5120          // nodes per bin; LDS acc = 5120*6*4 = 120 KB
#define NBINS 20                // covers 102400 >= 100000 nodes
#define NSUBC 12                // edge sub-slices for counting pass

// ---------------------------------------------------------------------------
// deg zero-init (ws is poisoned 0xAA every call).
// ---------------------------------------------------------------------------
__global__ void zero_deg(int* __restrict__ deg, int n) {
    int i = blockIdx.x * blockDim.x + threadIdx.x;
    if (i < n) deg[i] = 0;
}

// ---------------------------------------------------------------------------
// Binned degree count: block = (bin, sub). LDS int histogram over the bin's
// 5120 nodes; stream an edge-col slice with int4 loads; flush with one
// global int atomic per (block, touched node) — ~1.2M atomics vs 3.2M.
// ---------------------------------------------------------------------------
__global__ void count_binned(const int* __restrict__ col, int e,
                             int* __restrict__ deg, int n) {
    extern __shared__ int hist[];                // BIN_NODES ints = 20 KB
    int bin = blockIdx.x / NSUBC;
    int sub = blockIdx.x % NSUBC;
    int lo = bin * BIN_NODES;
    for (int j = threadIdx.x; j < BIN_NODES; j += blockDim.x) hist[j] = 0;
    __syncthreads();

    const int4* colv = (const int4*)col;
    int e4 = e >> 2;
    int chunk = (e4 + NSUBC - 1) / NSUBC;
    int start = sub * chunk;
    int end = min(start + chunk, e4);
    for (int i = start + (int)threadIdx.x; i < end; i += (int)blockDim.x) {
        int4 c4 = colv[i];
        int cc[4] = {c4.x, c4.y, c4.z, c4.w};
#pragma unroll
        for (int j = 0; j < 4; ++j) {
            unsigned l = (unsigned)(cc[j] - lo);
            if (l < (unsigned)BIN_NODES) atomicAdd(&hist[l], 1);
        }
    }
    // scalar tail (e not multiple of 4), handled once per bin by sub 0
    if (sub == 0) {
        for (int i = (e4 << 2) + (int)threadIdx.x; i < e; i += (int)blockDim.x) {
            unsigned l = (unsigned)(col[i] - lo);
            if (l < (unsigned)BIN_NODES) atomicAdd(&hist[l], 1);
        }
    }
    __syncthreads();
    for (int j = threadIdx.x; j < BIN_NODES; j += blockDim.x) {
        int h = hist[j];
        int node = lo + j;
        if (h > 0 && node < n) atomicAdd(&deg[node], h);
    }
}

// ---------------------------------------------------------------------------
// dis = rsqrt(deg+1); datom[i] = [dis*atom[i][0..4], dis, 0, 0] (32B aligned).
// Pre-scaling by dis[r] moves the source-side multiply out of the edge loop.
// ---------------------------------------------------------------------------
__global__ void dis_datom(const int* __restrict__ deg, const float* __restrict__ atom,
                          float* __restrict__ datom, int n) {
    int i = blockIdx.x * blockDim.x + threadIdx.x;
    if (i >= n) return;
    float d = rsqrtf((float)(deg[i] + 1));
    const float* ap = atom + (size_t)i * N_IN;
    float4 w0 = make_float4(d * ap[0], d * ap[1], d * ap[2], d * ap[3]);
    float4 w1 = make_float4(d * ap[4], d, 0.0f, 0.0f);
    float4* dp = (float4*)(datom + (size_t)i * 8);
    dp[0] = w0;
    dp[1] = w1;
}

// ---------------------------------------------------------------------------
// Binned accumulate: block = (bin, sub). LDS acc[5120][6] fp32. Stream an
// edge slice (row+col int4, coalesced); for col in bin: 6 LDS float atomics
// of datom[row][0..5]. Flush coalesced to per-block scratch slab.
// ---------------------------------------------------------------------------
__global__ void accum_binned(const int* __restrict__ row, const int* __restrict__ col,
                             int e, const float4* __restrict__ datom4,
                             float* __restrict__ accp, int nsub) {
    extern __shared__ float acc[];               // BIN_NODES*6 = 120 KB
    int bin = blockIdx.x / nsub;
    int sub = blockIdx.x % nsub;
    int lo = bin * BIN_NODES;
    for (int j = threadIdx.x; j < BIN_NODES * 6; j += blockDim.x) acc[j] = 0.0f;
    __syncthreads();

    const int4* colv = (const int4*)col;
    const int4* rowv = (const int4*)row;
    int e4 = e >> 2;
    int chunk = (e4 + nsub - 1) / nsub;
    int start = sub * chunk;
    int end = min(start + chunk, e4);
    for (int i = start + (int)threadIdx.x; i < end; i += (int)blockDim.x) {
        int4 c4 = colv[i];
        int4 r4 = rowv[i];
        int cc[4] = {c4.x, c4.y, c4.z, c4.w};
        int rr[4] = {r4.x, r4.y, r4.z, r4.w};
#pragma unroll
        for (int j = 0; j < 4; ++j) {
            unsigned l = (unsigned)(cc[j] - lo);
            if (l < (unsigned)BIN_NODES) {
                size_t r = (size_t)rr[j];
                float4 d0 = datom4[r * 2];
                float4 d1 = datom4[r * 2 + 1];
                float* a = acc + l * 6;
                atomicAdd(a + 0, d0.x);
                atomicAdd(a + 1, d0.y);
                atomicAdd(a + 2, d0.z);
                atomicAdd(a + 3, d0.w);
                atomicAdd(a + 4, d1.x);
                atomicAdd(a + 5, d1.y);
            }
        }
    }
    if (sub == 0) {
        for (int i = (e4 << 2) + (int)threadIdx.x; i < e; i += (int)blockDim.x) {
            unsigned l = (unsigned)(col[i] - lo);
            if (l < (unsigned)BIN_NODES) {
                size_t r = (size_t)row[i];
                float4 d0 = datom4[r * 2];
                float4 d1 = datom4[r * 2 + 1];
                float* a = acc + l * 6;
                atomicAdd(a + 0, d0.x);
                atomicAdd(a + 1, d0.y);
                atomicAdd(a + 2, d0.z);
                atomicAdd(a + 3, d0.w);
                atomicAdd(a + 4, d1.x);
                atomicAdd(a + 5, d1.y);
            }
        }
    }
    __syncthreads();
    float* dst = accp + (size_t)blockIdx.x * (BIN_NODES * 6);
    for (int j = threadIdx.x; j < BIN_NODES * 6; j += blockDim.x) dst[j] = acc[j];
}

// ---------------------------------------------------------------------------
// Final: per node, sum nsub partials (6 floats), fold self-loop via datom,
// apply W/b (wave-uniform, s_load broadcast), ReLU, 4x float4 store.
// out[c] = relu( (dis*s5 + dis*datom[c][0..4]) @ W^T + (dis*s1 + dis^2) * b )
// ---------------------------------------------------------------------------
__global__ void final_kernel(const float* __restrict__ accp, const float* __restrict__ datom,
                             const float* __restrict__ W, const float* __restrict__ b,
                             float* __restrict__ out, int n, int nsub) {
    int i = blockIdx.x * blockDim.x + threadIdx.x;
    if (i >= n) return;
    int bin = i / BIN_NODES;
    int l = i - bin * BIN_NODES;
    float s[6] = {0.f, 0.f, 0.f, 0.f, 0.f, 0.f};
    for (int sb = 0; sb < nsub; ++sb) {
        const float* p = accp + (size_t)(bin * nsub + sb) * (BIN_NODES * 6) + (size_t)l * 6;
#pragma unroll
        for (int k = 0; k < 6; ++k) s[k] += p[k];
    }
    const float* dp = datom + (size_t)i * 8;
    float d = dp[5];                       // dis[i]
    float t5[5];
#pragma unroll
    for (int k = 0; k < 5; ++k) t5[k] = d * (s[k] + dp[k]);   // dp[k]=dis*atom -> dis^2*atom
    float t1 = d * (s[5] + d);             // dis*s1 + dis^2
    float ov[N_OUT];
#pragma unroll
    for (int o = 0; o < N_OUT; ++o) {
        float a = b[o] * t1;
#pragma unroll
        for (int k = 0; k < 5; ++k) a = fmaf(W[o * N_IN + k], t5[k], a);
        ov[o] = fmaxf(a, 0.0f);
    }
    float4* op = (float4*)(out + (size_t)i * N_OUT);
#pragma unroll
    for (int q = 0; q < 4; ++q)
        op[q] = make_float4(ov[4 * q], ov[4 * q + 1], ov[4 * q + 2], ov[4 * q + 3]);
}

extern "C" void kernel_launch(void* const* d_in, const int* in_sizes, int n_in,
                              void* d_out, int out_size, void* d_ws, size_t ws_size,
                              hipStream_t stream) {
    const float* atom = (const float*)d_in[0];
    const int*   eidx = (const int*)d_in[1];   // [2, E] int32: row then col
    const float* W    = (const float*)d_in[2];
    const float* b    = (const float*)d_in[3];
    float* out = (float*)d_out;

    int n = in_sizes[0] / N_IN;       // 100000
    int e = in_sizes[1] / 2;          // 3200000
    const int* row = eidx;
    const int* col = eidx + e;

    // Workspace: deg[n] i32 | datom[n*8] f32 | accp[NBINS*nsub*5120*6] f32
    auto align256 = [](size_t v) { return (v + 255) & ~(size_t)255; };
    char* w = (char*)d_ws;
    int*   deg   = (int*)w;    w += align256((size_t)n * 4);
    float* datom = (float*)w;  w += align256((size_t)n * 8 * 4);
    float* accp  = (float*)w;
    size_t used_fixed = (size_t)(w - (char*)d_ws);

    // Adaptive sub-slice count for the accumulate pass (scratch-bound).
    size_t per_sub = (size_t)NBINS * BIN_NODES * 6 * 4;   // 2,457,600 B
    int nsub = 12;
    if (ws_size > used_fixed) {
        size_t fit = (ws_size - used_fixed) / per_sub;
        if (fit < (size_t)nsub) nsub = (int)fit;
    } else {
        nsub = 1;
    }
    if (nsub < 1) nsub = 1;

    const int B = 256;
    zero_deg<<<(n + B - 1) / B, B, 0, stream>>>(deg, n);
    count_binned<<<NBINS * NSUBC, 1024, BIN_NODES * sizeof(int), stream>>>(col, e, deg, n);
    dis_datom<<<(n + B - 1) / B, B, 0, stream>>>(deg, atom, datom, n);
    accum_binned<<<NBINS * nsub, 1024, BIN_NODES * 6 * sizeof(float), stream>>>(
        row, col, e, (const float4*)datom, accp, nsub);
    final_kernel<<<(n + B - 1) / B, B, 0, stream>>>(accp, datom, W, b, out, n, nsub);
}

// Round 4
// 226.862 us; speedup vs baseline: 3.8776x; 1.1006x over previous
//
#include <hip/hip_runtime.h>

#define N_IN 5
#define N_OUT 16
#define NB 50            // bins; NB*BN = 102400 >= 100000 nodes
#define BN 2048          // nodes per bin (power of 2: bin = c>>11, l = c&2047)
#define NSUB 5           // sub-blocks per bin for degcount/accum (50*5=250 blocks)
// Packed edge: (l << 17) | row. Requires n <= 131072 (here n = 100000).

// ---------------------------------------------------------------------------
// Zero deg[n] and counts[NB] (ws poisoned every call).
// ---------------------------------------------------------------------------
__global__ void zero_kernel(int* __restrict__ deg, int n, int* __restrict__ counts) {
    int i = blockIdx.x * blockDim.x + threadIdx.x;
    if (i < n) deg[i] = 0;
    if (i < NB) counts[i] = 0;
}

// ---------------------------------------------------------------------------
// Bin histogram: single coalesced pass over col, 50-entry LDS hist.
// ---------------------------------------------------------------------------
__global__ void hist_bins(const int* __restrict__ col, int e, int* __restrict__ counts) {
    __shared__ int h[NB];
    if (threadIdx.x < NB) h[threadIdx.x] = 0;
    __syncthreads();
    const int4* colv = (const int4*)col;
    int e4 = e >> 2;
    for (int i = blockIdx.x * blockDim.x + threadIdx.x; i < e4;
         i += gridDim.x * blockDim.x) {
        int4 c = colv[i];
        atomicAdd(&h[c.x >> 11], 1);
        atomicAdd(&h[c.y >> 11], 1);
        atomicAdd(&h[c.z >> 11], 1);
        atomicAdd(&h[c.w >> 11], 1);
    }
    if (blockIdx.x == 0) {
        for (int i = (e4 << 2) + (int)threadIdx.x; i < e; i += (int)blockDim.x)
            atomicAdd(&h[col[i] >> 11], 1);
    }
    __syncthreads();
    if (threadIdx.x < NB) atomicAdd(&counts[threadIdx.x], h[threadIdx.x]);
}

// ---------------------------------------------------------------------------
// Exclusive scan of 50 counts -> bbase; cursor = copy for partition.
// ---------------------------------------------------------------------------
__global__ void scan_bins(const int* __restrict__ counts, int* __restrict__ bbase,
                          int* __restrict__ cursor) {
    if (threadIdx.x == 0) {
        int s = 0;
        for (int b = 0; b < NB; ++b) {
            bbase[b] = s;
            cursor[b] = s;
            s += counts[b];
        }
    }
}

// ---------------------------------------------------------------------------
// Partition: chunk-wise LDS re-binning. Per 4096-edge chunk: LDS hist ->
// one global cursor atomic per touched bucket -> packed write (l<<17)|row.
// Bucket runs of ~330 B per chunk keep L2 write-combining effective.
// ---------------------------------------------------------------------------
__global__ void partition_kernel(const int* __restrict__ row, const int* __restrict__ col,
                                 int e, int* __restrict__ eb, int* __restrict__ cursor) {
    __shared__ int hist[NB];
    __shared__ int base[NB];
    __shared__ int lofs[NB];
    int e4 = e >> 2;
    int nchunk = (e4 + 1023) / 1024;
    const int4* rowv = (const int4*)row;
    const int4* colv = (const int4*)col;
    for (int ch = blockIdx.x; ch < nchunk; ch += gridDim.x) {
        int i = ch * 1024 + threadIdx.x;
        bool valid = i < e4;
        int rr[4], cc[4], bb[4];
        if (valid) {
            int4 r4 = rowv[i];
            int4 c4 = colv[i];
            rr[0] = r4.x; rr[1] = r4.y; rr[2] = r4.z; rr[3] = r4.w;
            cc[0] = c4.x; cc[1] = c4.y; cc[2] = c4.z; cc[3] = c4.w;
        }
        if (threadIdx.x < NB) { hist[threadIdx.x] = 0; lofs[threadIdx.x] = 0; }
        __syncthreads();
        if (valid) {
#pragma unroll
            for (int j = 0; j < 4; ++j) {
                bb[j] = cc[j] >> 11;
                atomicAdd(&hist[bb[j]], 1);
            }
        }
        __syncthreads();
        if (threadIdx.x < NB) {
            int h = hist[threadIdx.x];
            base[threadIdx.x] = h ? atomicAdd(&cursor[threadIdx.x], h) : 0;
        }
        __syncthreads();
        if (valid) {
#pragma unroll
            for (int j = 0; j < 4; ++j) {
                int p = atomicAdd(&lofs[bb[j]], 1);
                eb[base[bb[j]] + p] = ((cc[j] & (BN - 1)) << 17) | rr[j];
            }
        }
        __syncthreads();
    }
    if (blockIdx.x == 0) {   // scalar tail (e % 4)
        for (int i = (e4 << 2) + (int)threadIdx.x; i < e; i += (int)blockDim.x) {
            int c = col[i];
            int p = atomicAdd(&cursor[c >> 11], 1);
            eb[p] = ((c & (BN - 1)) << 17) | row[i];
        }
    }
}

// ---------------------------------------------------------------------------
// Per-bin degree count from partitioned buckets (single 12.8 MB read).
// ---------------------------------------------------------------------------
__global__ void degcount(const int* __restrict__ eb, const int* __restrict__ bbase,
                         const int* __restrict__ counts, int* __restrict__ deg, int n) {
    __shared__ int hist[BN];   // 8 KB
    int bin = blockIdx.x / NSUB;
    int sub = blockIdx.x % NSUB;
    int lo = bin * BN;
    for (int j = threadIdx.x; j < BN; j += blockDim.x) hist[j] = 0;
    __syncthreads();
    int s0 = bbase[bin], cnt = counts[bin];
    int chunk = (cnt + NSUB - 1) / NSUB;
    int start = sub * chunk;
    int end = min(start + chunk, cnt);
    for (int i = s0 + start + (int)threadIdx.x; i < s0 + end; i += (int)blockDim.x)
        atomicAdd(&hist[eb[i] >> 17], 1);
    __syncthreads();
    for (int j = threadIdx.x; j < BN; j += blockDim.x) {
        int h = hist[j];
        int node = lo + j;
        if (h > 0 && node < n) atomicAdd(&deg[node], h);
    }
}

// ---------------------------------------------------------------------------
// dis = rsqrt(deg+1); datom[i] = [dis*atom[0..4], dis, 0, 0] (32 B).
// ---------------------------------------------------------------------------
__global__ void dis_datom(const int* __restrict__ deg, const float* __restrict__ atom,
                          float* __restrict__ datom, int n) {
    int i = blockIdx.x * blockDim.x + threadIdx.x;
    if (i >= n) return;
    float d = rsqrtf((float)(deg[i] + 1));
    const float* ap = atom + (size_t)i * N_IN;
    float4* dp = (float4*)(datom + (size_t)i * 8);
    dp[0] = make_float4(d * ap[0], d * ap[1], d * ap[2], d * ap[3]);
    dp[1] = make_float4(d * ap[4], d, 0.0f, 0.0f);
}

// ---------------------------------------------------------------------------
// Accumulate: block = (bin, sub) reads ONLY its bucket slice (no filtering).
// 48 KB LDS acc -> 2 blocks/CU, 100% occupancy. 6 LDS float atomics/edge.
// ---------------------------------------------------------------------------
__global__ void accum_bin(const int* __restrict__ eb, const int* __restrict__ bbase,
                          const int* __restrict__ counts, const float4* __restrict__ datom4,
                          float* __restrict__ accp) {
    __shared__ float acc[BN * 6];   // 48 KB
    int bin = blockIdx.x / NSUB;
    int sub = blockIdx.x % NSUB;
    for (int j = threadIdx.x; j < BN * 6; j += blockDim.x) acc[j] = 0.0f;
    __syncthreads();
    int s0 = bbase[bin], cnt = counts[bin];
    int chunk = (cnt + NSUB - 1) / NSUB;
    int start = sub * chunk;
    int end = min(start + chunk, cnt);
    for (int i = s0 + start + (int)threadIdx.x; i < s0 + end; i += (int)blockDim.x) {
        int v = eb[i];
        int r = v & 0x1FFFF;
        int l = v >> 17;
        float4 d0 = datom4[2 * (size_t)r];
        float4 d1 = datom4[2 * (size_t)r + 1];
        float* a = acc + l * 6;
        atomicAdd(a + 0, d0.x);
        atomicAdd(a + 1, d0.y);
        atomicAdd(a + 2, d0.z);
        atomicAdd(a + 3, d0.w);
        atomicAdd(a + 4, d1.x);
        atomicAdd(a + 5, d1.y);
    }
    __syncthreads();
    float* dst = accp + (size_t)blockIdx.x * (BN * 6);
    for (int j = threadIdx.x; j < BN * 6; j += blockDim.x) dst[j] = acc[j];
}

// ---------------------------------------------------------------------------
// Final: sum NSUB partials, fold self-loop, apply W/b, ReLU, float4 stores.
// ---------------------------------------------------------------------------
__global__ void final_kernel(const float* __restrict__ accp, const float* __restrict__ datom,
                             const float* __restrict__ W, const float* __restrict__ b,
                             float* __restrict__ out, int n) {
    int i = blockIdx.x * blockDim.x + threadIdx.x;
    if (i >= n) return;
    int bin = i >> 11;
    int l = i & (BN - 1);
    float s[6] = {0.f, 0.f, 0.f, 0.f, 0.f, 0.f};
#pragma unroll
    for (int sb = 0; sb < NSUB; ++sb) {
        const float* p = accp + (size_t)(bin * NSUB + sb) * (BN * 6) + (size_t)l * 6;
#pragma unroll
        for (int k = 0; k < 6; ++k) s[k] += p[k];
    }
    const float* dp = datom + (size_t)i * 8;
    float d = dp[5];                           // dis[i]
    float t5[5];
#pragma unroll
    for (int k = 0; k < 5; ++k) t5[k] = d * (s[k] + dp[k]);  // + dis^2*atom self term
    float t1 = d * (s[5] + d);
    float ov[N_OUT];
#pragma unroll
    for (int o = 0; o < N_OUT; ++o) {
        float a = b[o] * t1;
#pragma unroll
        for (int k = 0; k < 5; ++k) a = fmaf(W[o * N_IN + k], t5[k], a);
        ov[o] = fmaxf(a, 0.0f);
    }
    float4* op = (float4*)(out + (size_t)i * N_OUT);
#pragma unroll
    for (int q = 0; q < 4; ++q)
        op[q] = make_float4(ov[4 * q], ov[4 * q + 1], ov[4 * q + 2], ov[4 * q + 3]);
}

extern "C" void kernel_launch(void* const* d_in, const int* in_sizes, int n_in,
                              void* d_out, int out_size, void* d_ws, size_t ws_size,
                              hipStream_t stream) {
    const float* atom = (const float*)d_in[0];
    const int*   eidx = (const int*)d_in[1];   // [2, E] int32: row then col
    const float* W    = (const float*)d_in[2];
    const float* b    = (const float*)d_in[3];
    float* out = (float*)d_out;

    int n = in_sizes[0] / N_IN;       // 100000
    int e = in_sizes[1] / 2;          // 3200000
    const int* row = eidx;
    const int* col = eidx + e;

    // ws: deg[n] | datom[n*8] f32 | eb[e] i32 | counts/bbase/cursor[NB] |
    //     accp[NB*NSUB*BN*6] f32          total ~28.7 MB
    auto align256 = [](size_t v) { return (v + 255) & ~(size_t)255; };
    char* w = (char*)d_ws;
    int*   deg    = (int*)w;    w += align256((size_t)n * 4);
    float* datom  = (float*)w;  w += align256((size_t)n * 8 * 4);
    int*   eb     = (int*)w;    w += align256((size_t)e * 4);
    int*   counts = (int*)w;    w += align256(NB * 4);
    int*   bbase  = (int*)w;    w += align256(NB * 4);
    int*   cursor = (int*)w;    w += align256(NB * 4);
    float* accp   = (float*)w;

    const int B = 256;
    zero_kernel<<<(n + B - 1) / B, B, 0, stream>>>(deg, n, counts);
    hist_bins<<<256, 1024, 0, stream>>>(col, e, counts);
    scan_bins<<<1, 64, 0, stream>>>(counts, bbase, cursor);
    partition_kernel<<<256, 1024, 0, stream>>>(row, col, e, eb, cursor);
    degcount<<<NB * NSUB, 1024, 0, stream>>>(eb, bbase, counts, deg, n);
    dis_datom<<<(n + B - 1) / B, B, 0, stream>>>(deg, atom, datom, n);
    accum_bin<<<NB * NSUB, 1024, 0, stream>>>(eb, bbase, counts, (const float4*)datom, accp);
    final_kernel<<<(n + B - 1) / B, B, 0, stream>>>(accp, datom, W, b, out, n);
}